// Round 6
// baseline (42.956 us; speedup 1.0000x reference)
//
#include <hip/hip_runtime.h>
#include <cmath>

typedef __attribute__((ext_vector_type(8))) short short8;
typedef __attribute__((ext_vector_type(4))) float f32x4;

#define NB 32
#define MU_OUT_SZ (NB*100*64)   // 204800
#define LDAP 56                 // shorts per (h,w) cell in LDS (112 B padded)

__device__ inline unsigned short f2bf(float f) {
  unsigned u = __builtin_bit_cast(unsigned, f);
  u += 0x7fffu + ((u >> 16) & 1u);
  return (unsigned short)(u >> 16);
}

// ---------------- prepW: pack W and (W^2 + softplus) into MFMA B-frag order ----------------
__global__ __launch_bounds__(256) void prepW(
    const float* __restrict__ w_mu, const float* __restrict__ w_sigma,
    unsigned short* __restrict__ wf) {
  const int wid = blockIdx.x * 256 + threadIdx.x;   // 0..12799
  const int kind = wid >= 6400 ? 1 : 0;             // 0: W, 1: W^2 + sp
  const int fid = kind ? wid - 6400 : wid;
  const int ij = fid >> 8;                          // 0..24
  const int rest = fid & 255;
  const int n = rest >> 6, l = rest & 63;
  const int col = n * 16 + (l & 15);                // output channel k
  const int m0 = ij * 32 + (l >> 4) * 8;            // K-row base
  const float sp = log1pf(expf(w_sigma[col]));
  unsigned short v[8];
#pragma unroll
  for (int i = 0; i < 8; ++i) {
    float wv = w_mu[(m0 + i) * 64 + col];
    float x = kind ? (wv * wv + sp) : wv;
    v[i] = f2bf(x);
  }
  uint4 pk;
  pk.x = v[0] | ((unsigned)v[1] << 16);
  pk.y = v[2] | ((unsigned)v[3] << 16);
  pk.z = v[4] | ((unsigned)v[5] << 16);
  pk.w = v[6] | ((unsigned)v[7] << 16);
  *(uint4*)(wf + (size_t)((ij * 8 + kind * 4 + n) * 64 + l) * 8) = pk;
}

// ---------------- fused2: per block = (b, 2 p-rows): G rows + mu_out + dv + stream slab ----------------
__global__ __launch_bounds__(256) void fused2(
    const float* __restrict__ mu_in, const float* __restrict__ Sigma_in,
    const float* __restrict__ w_sigma, const unsigned short* __restrict__ wf,
    float* __restrict__ out) {
  __shared__ unsigned short mu_sh[196 * LDAP];   // 21952 B
  __shared__ unsigned short sd_sh[70 * LDAP];    // 5 h-rows x 14 w, 7840 B
  __shared__ float g_sh[2][100];
  __shared__ float dv_sh[2][64];
  const int s = blockIdx.x;            // slab 0..49 -> p rows {2s, 2s+1}
  const int b = blockIdx.y;
  const int t = threadIdx.x, l = t & 63, w = t >> 6;
  const int p0 = 2 * s;
  const int ph = p0 / 10;              // both rows share ph (pairs never straddle)

  // ---- stage mu[b] (all 196 cells) as bf16, padded ----
  const float4* mu4 = (const float4*)(mu_in + (size_t)b * 6272);
  for (int f = t; f < 1568; f += 256) {
    const float4 v = mu4[f];
    const int row = f >> 3, c = (f & 7) * 4;
    ushort4 pv;
    pv.x = f2bf(v.x); pv.y = f2bf(v.y); pv.z = f2bf(v.z); pv.w = f2bf(v.w);
    *(ushort4*)(mu_sh + row * LDAP + c) = pv;
  }
  // ---- stage Sigma-diag for the 5 needed h-rows ----
  for (int f = t; f < 560; f += 256) {
    const int hl = f / 112;            // 0..4
    const int rem = f - hl * 112;
    const int ww = rem >> 3, c = (rem & 7) * 4;
    const int n = (ph + hl) * 14 + ww;
    const float4 v = *(const float4*)(Sigma_in +
        ((size_t)(b * 196 + n) * 196 + n) * 32 + c);
    ushort4 pv;
    pv.x = f2bf(v.x); pv.y = f2bf(v.y); pv.z = f2bf(v.z); pv.w = f2bf(v.w);
    *(ushort4*)(sd_sh + (hl * 14 + ww) * LDAP + c) = pv;
  }
  __syncthreads();

  // ---- MFMA phase ----
  const int laneP = l & 15, g16 = (l >> 4) * 8;
  const int pA = (p0 + laneP > 99) ? 99 : p0 + laneP;      // rows >=2 are dummies
  const int baseA = ((pA / 10) * 14 + (pA % 10)) * LDAP + g16;
  const int pS = p0 + (laneP < 2 ? laneP : 1);             // clamp into slab
  const int baseS = (pS % 10) * LDAP + g16;                // local h = i (ph aligned)
  const int tile0 = w;                                     // G col tiles
  const int tile1 = (w < 3) ? w + 4 : -1;
  int q0 = tile0 * 16 + laneP; const int q0c = q0 > 99 ? 99 : q0;
  const int baseB0 = ((q0c / 10) * 14 + (q0c % 10)) * LDAP + g16;
  int q1 = 0, baseB1 = 0;
  if (tile1 >= 0) {
    q1 = tile1 * 16 + laneP; const int q1c = q1 > 99 ? 99 : q1;
    baseB1 = ((q1c / 10) * 14 + (q1c % 10)) * LDAP + g16;
  }
  f32x4 aG0 = {}, aG1 = {}, aM = {}, aD = {};
#pragma unroll
  for (int ij = 0; ij < 25; ++ij) {
    const int off = ((ij / 5) * 14 + (ij % 5)) * LDAP;
    const short8 fA = *(const short8*)(mu_sh + baseA + off);
    const short8 fB0 = *(const short8*)(mu_sh + baseB0 + off);
    aG0 = __builtin_amdgcn_mfma_f32_16x16x32_bf16(fA, fB0, aG0, 0, 0, 0);
    if (tile1 >= 0) {
      const short8 fB1 = *(const short8*)(mu_sh + baseB1 + off);
      aG1 = __builtin_amdgcn_mfma_f32_16x16x32_bf16(fA, fB1, aG1, 0, 0, 0);
    }
    const short8 bw = *(const short8*)(wf + (size_t)((ij * 8 + w) * 64 + l) * 8);
    aM = __builtin_amdgcn_mfma_f32_16x16x32_bf16(fA, bw, aM, 0, 0, 0);
    const short8 fS = *(const short8*)(sd_sh + baseS + off);
    const short8 b2 = *(const short8*)(wf + (size_t)((ij * 8 + 4 + w) * 64 + l) * 8);
    aD = __builtin_amdgcn_mfma_f32_16x16x32_bf16(fS, b2, aD, 0, 0, 0);
  }
  // C layout: col = l&15, row = (l>>4)*4 + j -> rows 0,1 live in lanes 0..15, j=0,1
  if (l < 16) {
#pragma unroll
    for (int j = 0; j < 2; ++j) {
      if (q0 < 100) g_sh[j][q0] = aG0[j];
      if (tile1 >= 0 && q1 < 100) g_sh[j][q1] = aG1[j];
      const int k = w * 16 + laneP;
      out[((size_t)b * 100 + p0 + j) * 64 + k] = aM[j];
      dv_sh[j][k] = aD[j];
    }
  }
  __syncthreads();

  // ---- write phase: 2 x 100 x 64 floats = 3200 float4, uniform ----
  const int k4 = (t & 15) * 4;         // constant per thread
  const float4 wsv = *(const float4*)(w_sigma + k4);
  f32x4 sp4;
  sp4.x = log1pf(expf(wsv.x));
  sp4.y = log1pf(expf(wsv.y));
  sp4.z = log1pf(expf(wsv.z));
  sp4.w = log1pf(expf(wsv.w));
  float* sig = out + MU_OUT_SZ + ((size_t)(b * 100 + p0) * 100) * 64;
  for (int l4 = t; l4 < 3200; l4 += 256) {
    const int row = (l4 >= 1600) ? 1 : 0;
    const int rem = l4 - row * 1600;
    const int q = rem >> 4;
    const float g = g_sh[row][q];
    f32x4 v;
    v.x = sp4.x * g; v.y = sp4.y * g; v.z = sp4.z * g; v.w = sp4.w * g;
    if (q == p0 + row) {
      const float4 dvv = *(const float4*)&dv_sh[row][k4];
      v.x += dvv.x; v.y += dvv.y; v.z += dvv.z; v.w += dvv.w;
    }
    v.x = (q == k4)     ? fabsf(v.x) : v.x;
    v.y = (q == k4 + 1) ? fabsf(v.y) : v.y;
    v.z = (q == k4 + 2) ? fabsf(v.z) : v.z;
    v.w = (q == k4 + 3) ? fabsf(v.w) : v.w;
    __builtin_nontemporal_store(v, (f32x4*)(sig + (size_t)l4 * 4));
  }
}

extern "C" void kernel_launch(void* const* d_in, const int* in_sizes, int n_in,
                              void* d_out, int out_size, void* d_ws, size_t ws_size,
                              hipStream_t stream) {
  const float* mu_in    = (const float*)d_in[0];
  const float* Sigma_in = (const float*)d_in[1];
  const float* w_mu     = (const float*)d_in[2];
  const float* w_sigma  = (const float*)d_in[3];
  float* out = (float*)d_out;
  unsigned short* wf = (unsigned short*)d_ws;   // 204800 B

  prepW<<<50, 256, 0, stream>>>(w_mu, w_sigma, wf);
  fused2<<<dim3(50, NB), 256, 0, stream>>>(mu_in, Sigma_in, w_sigma, wf, out);
}

// Round 7
// 33.422 us; speedup vs baseline: 1.2853x; 1.2853x over previous
//
#include <hip/hip_runtime.h>
#include <cmath>

typedef __attribute__((ext_vector_type(8))) short short8;
typedef __attribute__((ext_vector_type(4))) float f32x4;

#define NB 32
#define MU_OUT_SZ (NB*100*64)   // 204800
#define LDAP 56                 // shorts per (h,w) cell in LDS (112 B padded)

// ws byte offsets
#define WS_WF 0                 // bf16 frags [25][2][4][64][8] = 204800 B
#define WS_G  204800            // f32 [32][100][100] = 1280000 B
#define WS_DV 1484800           // f32 [32][100][64]  = 819200 B

__device__ inline unsigned short f2bf(float f) {
  unsigned u = __builtin_bit_cast(unsigned, f);
  u += 0x7fffu + ((u >> 16) & 1u);
  return (unsigned short)(u >> 16);
}

// ---------------- prepW: coalesced stage of w slice -> LDS -> fragment pack ----------------
__global__ __launch_bounds__(256) void prepW(
    const float* __restrict__ w_mu, const float* __restrict__ w_sigma,
    unsigned short* __restrict__ wf) {
  __shared__ float wsh[2048];              // this ij's 32 K-rows x 64 cols (8 KB)
  const int ij = blockIdx.x, t = threadIdx.x;
  const float4* src = (const float4*)(w_mu + (size_t)ij * 2048);
  ((float4*)wsh)[t]       = src[t];
  ((float4*)wsh)[t + 256] = src[t + 256];
  __syncthreads();
#pragma unroll
  for (int id0 = 0; id0 < 512; id0 += 256) {
    const int id = id0 + t;
    const int kind = id >> 8;              // 0: W, 1: W^2 + sp
    const int rest = id & 255;
    const int n = rest >> 6, l = rest & 63;
    const int col = n * 16 + (l & 15);     // output channel k
    const int m0 = (l >> 4) * 8;           // K-row base within this ij
    const float sp = log1pf(expf(w_sigma[col]));
    unsigned short v[8];
#pragma unroll
    for (int i = 0; i < 8; ++i) {
      const float wv = wsh[(m0 + i) * 64 + col];
      const float x = kind ? (wv * wv + sp) : wv;
      v[i] = f2bf(x);
    }
    uint4 pk;
    pk.x = v[0] | ((unsigned)v[1] << 16);
    pk.y = v[2] | ((unsigned)v[3] << 16);
    pk.z = v[4] | ((unsigned)v[5] << 16);
    pk.w = v[6] | ((unsigned)v[7] << 16);
    *(uint4*)(wf + (size_t)((ij * 8 + kind * 4 + n) * 64 + l) * 8) = pk;
  }
}

// ---------------- gemm: 512 thr, 8 waves: 7 G-tiles + 4 mu + 4 dv ----------------
__global__ __launch_bounds__(512) void gemm(
    const float* __restrict__ mu_in, const float* __restrict__ Sigma_in,
    const unsigned short* __restrict__ wf,
    float* __restrict__ G, float* __restrict__ dv, float* __restrict__ out) {
  __shared__ unsigned short mu_sh[196 * LDAP];   // 21952 B
  __shared__ unsigned short sd_sh[196 * LDAP];   // 21952 B
  const int r = blockIdx.x;            // p-row tile 0..6
  const int b = blockIdx.y;
  const int t = threadIdx.x, l = t & 63, w = t >> 6;

  // stage mu[b] and diag(Sigma[b]) as bf16, padded rows
  const float4* mu4 = (const float4*)(mu_in + (size_t)b * 6272);
  for (int f = t; f < 1568; f += 512) {
    const float4 v = mu4[f];
    const int row = f >> 3, c = (f & 7) * 4;
    ushort4 pv;
    pv.x = f2bf(v.x); pv.y = f2bf(v.y); pv.z = f2bf(v.z); pv.w = f2bf(v.w);
    *(ushort4*)(mu_sh + row * LDAP + c) = pv;
    const float4 s = *(const float4*)(Sigma_in +
        ((size_t)(b * 196 + row) * 196 + row) * 32 + c);
    ushort4 ps;
    ps.x = f2bf(s.x); ps.y = f2bf(s.y); ps.z = f2bf(s.z); ps.w = f2bf(s.w);
    *(ushort4*)(sd_sh + row * LDAP + c) = ps;
  }
  __syncthreads();

  const int laneP = l & 15, g16 = (l >> 4) * 8;
  const int pA = (r * 16 + laneP > 99) ? 99 : r * 16 + laneP;
  const int baseA = ((pA / 10) * 14 + (pA % 10)) * LDAP + g16;
  const bool doG = (w < 7);
  const int q = w * 16 + laneP;                    // G col (waves 0..6)
  const int qc = q > 99 ? 99 : q;
  const int baseB = ((qc / 10) * 14 + (qc % 10)) * LDAP + g16;
  const bool doMu = (w < 4);
  const int n = doMu ? w : (w - 4);                // k-tile
  const int kslot = doMu ? n : (4 + n);            // wf tile index

  const short8* wfp = (const short8*)wf;           // [(ij*8 + kslot)*64 + l]
  short8 fw = wfp[(size_t)kslot * 64 + l];         // prefetch ij=0
  f32x4 aG = {}, aX = {};
  for (int ij = 0; ij < 25; ++ij) {
    const short8 fw_n = (ij < 24) ? wfp[(size_t)((ij + 1) * 8 + kslot) * 64 + l] : fw;
    const int off = ((ij / 5) * 14 + (ij % 5)) * LDAP;
    if (doG) {
      const short8 fA = *(const short8*)(mu_sh + baseA + off);
      const short8 fB = *(const short8*)(mu_sh + baseB + off);
      aG = __builtin_amdgcn_mfma_f32_16x16x32_bf16(fA, fB, aG, 0, 0, 0);
      if (doMu) {
        aX = __builtin_amdgcn_mfma_f32_16x16x32_bf16(fA, fw, aX, 0, 0, 0);
      } else {
        const short8 fS = *(const short8*)(sd_sh + baseA + off);
        aX = __builtin_amdgcn_mfma_f32_16x16x32_bf16(fS, fw, aX, 0, 0, 0);
      }
    } else {
      const short8 fS = *(const short8*)(sd_sh + baseA + off);
      aX = __builtin_amdgcn_mfma_f32_16x16x32_bf16(fS, fw, aX, 0, 0, 0);
    }
    fw = fw_n;
  }

  const int prow0 = (l >> 4) * 4;
  if (doG && q < 100) {
    float* Gb = G + (size_t)b * 10000;
#pragma unroll
    for (int j = 0; j < 4; ++j) {
      const int row = r * 16 + prow0 + j;
      if (row < 100) Gb[row * 100 + q] = aG[j];
    }
  }
  const int k = n * 16 + laneP;
  if (doMu) {
    float* mo = out + (size_t)b * 6400;
#pragma unroll
    for (int j = 0; j < 4; ++j) {
      const int p = r * 16 + prow0 + j;
      if (p < 100) mo[p * 64 + k] = aX[j];
    }
  } else {
    float* dvb = dv + (size_t)b * 6400;
#pragma unroll
    for (int j = 0; j < 4; ++j) {
      const int p = r * 16 + prow0 + j;
      if (p < 100) dvb[p * 64 + k] = aX[j];
    }
  }
}

// ---------------- writer: balanced grid-stride stream of Sigma_out ----------------
__global__ __launch_bounds__(256) void writer(
    const float* __restrict__ G, const float* __restrict__ dv,
    const float* __restrict__ w_sigma, float* __restrict__ out) {
  const unsigned tid = blockIdx.x * 256 + threadIdx.x;
  const int k4 = (tid & 15) * 4;       // constant per thread (stride % 16 == 0)
  const float4 wsv = *(const float4*)(w_sigma + k4);
  f32x4 sp4;
  sp4.x = log1pf(expf(wsv.x));
  sp4.y = log1pf(expf(wsv.y));
  sp4.z = log1pf(expf(wsv.z));
  sp4.w = log1pf(expf(wsv.w));
  float* sig = out + MU_OUT_SZ;
  for (unsigned l4 = tid; l4 < 5120000u; l4 += 524288u) {
    const unsigned rr = l4 >> 4;        // = (b*100 + p)*100 + q
    const unsigned q = rr % 100u;
    const unsigned pq = rr / 100u;      // = b*100 + p
    const unsigned p = pq % 100u;
    const float g = G[rr];
    f32x4 v;
    v.x = sp4.x * g; v.y = sp4.y * g; v.z = sp4.z * g; v.w = sp4.w * g;
    if (q == p) {
      const float4 dvv = *(const float4*)(dv + (size_t)pq * 64 + k4);
      v.x += dvv.x; v.y += dvv.y; v.z += dvv.z; v.w += dvv.w;
    }
    v.x = (q == (unsigned)k4)     ? fabsf(v.x) : v.x;
    v.y = (q == (unsigned)k4 + 1) ? fabsf(v.y) : v.y;
    v.z = (q == (unsigned)k4 + 2) ? fabsf(v.z) : v.z;
    v.w = (q == (unsigned)k4 + 3) ? fabsf(v.w) : v.w;
    __builtin_nontemporal_store(v, (f32x4*)(sig + (size_t)l4 * 4));
  }
}

extern "C" void kernel_launch(void* const* d_in, const int* in_sizes, int n_in,
                              void* d_out, int out_size, void* d_ws, size_t ws_size,
                              hipStream_t stream) {
  const float* mu_in    = (const float*)d_in[0];
  const float* Sigma_in = (const float*)d_in[1];
  const float* w_mu     = (const float*)d_in[2];
  const float* w_sigma  = (const float*)d_in[3];
  float* out = (float*)d_out;
  unsigned char* ws = (unsigned char*)d_ws;
  unsigned short* wf = (unsigned short*)(ws + WS_WF);
  float* G  = (float*)(ws + WS_G);
  float* dv = (float*)(ws + WS_DV);

  prepW<<<25, 256, 0, stream>>>(w_mu, w_sigma, wf);
  gemm<<<dim3(7, NB), 512, 0, stream>>>(mu_in, Sigma_in, wf, G, dv, out);
  writer<<<2048, 256, 0, stream>>>(G, dv, w_sigma, out);
}

// Round 9
// 33.131 us; speedup vs baseline: 1.2966x; 1.0088x over previous
//
#include <hip/hip_runtime.h>
#include <cmath>

typedef __attribute__((ext_vector_type(8))) short short8;
typedef __attribute__((ext_vector_type(4))) float f32x4;

#define NB 32
#define MU_OUT_SZ (NB*100*64)   // 204800
#define LDAP 56                 // shorts per (h,w) cell in LDS (112 B padded)

__device__ inline unsigned short f2bf(float f) {
  unsigned u = __builtin_bit_cast(unsigned, f);
  u += 0x7fffu + ((u >> 16) & 1u);
  return (unsigned short)(u >> 16);
}

// ---------------- prepW: coalesced stage of w slice -> LDS -> fragment pack ----------------
// (verbatim from R7 — proven)
__global__ __launch_bounds__(256) void prepW(
    const float* __restrict__ w_mu, const float* __restrict__ w_sigma,
    unsigned short* __restrict__ wf) {
  __shared__ float wsh[2048];              // this ij's 32 K-rows x 64 cols (8 KB)
  const int ij = blockIdx.x, t = threadIdx.x;
  const float4* src = (const float4*)(w_mu + (size_t)ij * 2048);
  ((float4*)wsh)[t]       = src[t];
  ((float4*)wsh)[t + 256] = src[t + 256];
  __syncthreads();
#pragma unroll
  for (int id0 = 0; id0 < 512; id0 += 256) {
    const int id = id0 + t;
    const int kind = id >> 8;              // 0: W, 1: W^2 + sp
    const int rest = id & 255;
    const int n = rest >> 6, l = rest & 63;
    const int col = n * 16 + (l & 15);     // output channel k
    const int m0 = (l >> 4) * 8;           // K-row base within this ij
    const float sp = log1pf(expf(w_sigma[col]));
    unsigned short v[8];
#pragma unroll
    for (int i = 0; i < 8; ++i) {
      const float wv = wsh[(m0 + i) * 64 + col];
      const float x = kind ? (wv * wv + sp) : wv;
      v[i] = f2bf(x);
    }
    uint4 pk;
    pk.x = v[0] | ((unsigned)v[1] << 16);
    pk.y = v[2] | ((unsigned)v[3] << 16);
    pk.z = v[4] | ((unsigned)v[5] << 16);
    pk.w = v[6] | ((unsigned)v[7] << 16);
    *(uint4*)(wf + (size_t)((ij * 8 + kind * 4 + n) * 64 + l) * 8) = pk;
  }
}

// ---------------- fusedK: gemm (R7 structure) + LDS G/dv + direct Sigma_out stream ----------------
__global__ __launch_bounds__(512) void fusedK(
    const float* __restrict__ mu_in, const float* __restrict__ Sigma_in,
    const unsigned short* __restrict__ wf, const float* __restrict__ w_sigma,
    float* __restrict__ out) {
  __shared__ unsigned short mu_sh[196 * LDAP];   // 21952 B
  __shared__ unsigned short sd_sh[196 * LDAP];   // 21952 B
  __shared__ float g_sh[16][100];                // 6400 B
  __shared__ float dv_sh[16][64];                // 4096 B
  const int r = blockIdx.x;            // p-row tile 0..6
  const int b = blockIdx.y;
  const int t = threadIdx.x, l = t & 63, w = t >> 6;

  // ---- stage mu[b] and diag(Sigma[b]) as bf16, padded rows (R7 verbatim) ----
  const float4* mu4 = (const float4*)(mu_in + (size_t)b * 6272);
  for (int f = t; f < 1568; f += 512) {
    const float4 v = mu4[f];
    const int row = f >> 3, c = (f & 7) * 4;
    ushort4 pv;
    pv.x = f2bf(v.x); pv.y = f2bf(v.y); pv.z = f2bf(v.z); pv.w = f2bf(v.w);
    *(ushort4*)(mu_sh + row * LDAP + c) = pv;
    const float4 s = *(const float4*)(Sigma_in +
        ((size_t)(b * 196 + row) * 196 + row) * 32 + c);
    ushort4 ps;
    ps.x = f2bf(s.x); ps.y = f2bf(s.y); ps.z = f2bf(s.z); ps.w = f2bf(s.w);
    *(ushort4*)(sd_sh + row * LDAP + c) = ps;
  }
  __syncthreads();

  // ---- MFMA phase (R7 verbatim except G/dv -> LDS) ----
  const int laneP = l & 15, g16 = (l >> 4) * 8;
  const int pA = (r * 16 + laneP > 99) ? 99 : r * 16 + laneP;
  const int baseA = ((pA / 10) * 14 + (pA % 10)) * LDAP + g16;
  const bool doG = (w < 7);
  const int q = w * 16 + laneP;                    // G col (waves 0..6)
  const int qc = q > 99 ? 99 : q;
  const int baseB = ((qc / 10) * 14 + (qc % 10)) * LDAP + g16;
  const bool doMu = (w < 4);
  const int n = doMu ? w : (w - 4);                // k-tile
  const int kslot = doMu ? n : (4 + n);            // wf tile index

  const short8* wfp = (const short8*)wf;           // [(ij*8 + kslot)*64 + l]
  short8 fw = wfp[(size_t)kslot * 64 + l];         // prefetch ij=0
  f32x4 aG = {}, aX = {};
  for (int ij = 0; ij < 25; ++ij) {
    const short8 fw_n = (ij < 24) ? wfp[(size_t)((ij + 1) * 8 + kslot) * 64 + l] : fw;
    const int off = ((ij / 5) * 14 + (ij % 5)) * LDAP;
    if (doG) {
      const short8 fA = *(const short8*)(mu_sh + baseA + off);
      const short8 fB = *(const short8*)(mu_sh + baseB + off);
      aG = __builtin_amdgcn_mfma_f32_16x16x32_bf16(fA, fB, aG, 0, 0, 0);
      if (doMu) {
        aX = __builtin_amdgcn_mfma_f32_16x16x32_bf16(fA, fw, aX, 0, 0, 0);
      } else {
        const short8 fS = *(const short8*)(sd_sh + baseA + off);
        aX = __builtin_amdgcn_mfma_f32_16x16x32_bf16(fS, fw, aX, 0, 0, 0);
      }
    } else {
      const short8 fS = *(const short8*)(sd_sh + baseA + off);
      aX = __builtin_amdgcn_mfma_f32_16x16x32_bf16(fS, fw, aX, 0, 0, 0);
    }
    fw = fw_n;
  }

  const int prow0 = (l >> 4) * 4;
  if (doG && q < 100) {
#pragma unroll
    for (int j = 0; j < 4; ++j) g_sh[prow0 + j][q] = aG[j];
  }
  const int k = n * 16 + laneP;
  if (doMu) {
    float* mo = out + (size_t)b * 6400;
#pragma unroll
    for (int j = 0; j < 4; ++j) {
      const int p = r * 16 + prow0 + j;
      if (p < 100) mo[p * 64 + k] = aX[j];
    }
  } else {
#pragma unroll
    for (int j = 0; j < 4; ++j) dv_sh[prow0 + j][k] = aX[j];
  }
  __syncthreads();

  // ---- write phase: stream Sigma_out rows [16r, 16r+nrows) of batch b ----
  const int nrows = (r == 6) ? 4 : 16;
  const int p0 = r * 16;
  const int k4 = (t & 15) * 4;         // constant per thread (512 % 16 == 0)
  const float4 wsv = *(const float4*)(w_sigma + k4);
  f32x4 sp4;
  sp4.x = log1pf(expf(wsv.x));
  sp4.y = log1pf(expf(wsv.y));
  sp4.z = log1pf(expf(wsv.z));
  sp4.w = log1pf(expf(wsv.w));
  float* sig = out + MU_OUT_SZ + ((size_t)(b * 100 + p0) * 100) * 64;
  const int total = nrows * 1600;      // nrows * 100q * 16 float4
  for (int l4 = t; l4 < total; l4 += 512) {
    const int row = l4 / 1600;
    const int rem = l4 - row * 1600;
    const int qq = rem >> 4;
    const float g = g_sh[row][qq];
    f32x4 v;
    v.x = sp4.x * g; v.y = sp4.y * g; v.z = sp4.z * g; v.w = sp4.w * g;
    if (qq == p0 + row) {
      const float4 dvv = *(const float4*)&dv_sh[row][k4];
      v.x += dvv.x; v.y += dvv.y; v.z += dvv.z; v.w += dvv.w;
    }
    v.x = (qq == k4)     ? fabsf(v.x) : v.x;
    v.y = (qq == k4 + 1) ? fabsf(v.y) : v.y;
    v.z = (qq == k4 + 2) ? fabsf(v.z) : v.z;
    v.w = (qq == k4 + 3) ? fabsf(v.w) : v.w;
    __builtin_nontemporal_store(v, (f32x4*)(sig + (size_t)l4 * 4));
  }
}

extern "C" void kernel_launch(void* const* d_in, const int* in_sizes, int n_in,
                              void* d_out, int out_size, void* d_ws, size_t ws_size,
                              hipStream_t stream) {
  const float* mu_in    = (const float*)d_in[0];
  const float* Sigma_in = (const float*)d_in[1];
  const float* w_mu     = (const float*)d_in[2];
  const float* w_sigma  = (const float*)d_in[3];
  float* out = (float*)d_out;
  unsigned short* wf = (unsigned short*)d_ws;   // 204800 B

  prepW<<<25, 256, 0, stream>>>(w_mu, w_sigma, wf);
  fusedK<<<dim3(7, NB), 512, 0, stream>>>(mu_in, Sigma_in, wf, w_sigma, out);
}